// Round 14
// baseline (138.203 us; speedup 1.0000x reference)
//
#include <hip/hip_runtime.h>

// Problem constants (fixed by the reference's setup_inputs):
//   N = 100000 particles, D = 100 grid cells/dim, filter_size = 5 (radius 2).
// One particle per cell guaranteed (rng.choice replace=False).
static const int DG = 100;
static const int PGD = DG + 4;              // halo-padded dim: 104
static const int PCELLS = PGD * PGD * PGD;  // 1124864 cells

// Spatial tile per workgroup: 10 x 10 x 5 interior cells, +2 halo each side.
static const int TX = 10, TY = 10, TZ = 5;
static const int HX = TX + 4, HY = TY + 4, HZ = TZ + 4;   // 14,14,9
static const int HPLANE = HX * HY;                        // 196
static const int HCELLS = HPLANE * HZ;                    // 1764
static const int TCELLS = TX * TY * TZ;                   // 500
static const int NTX = DG / TX, NTY = DG / TY, NTZ = DG / TZ; // 10,10,20
static const int NTILES = NTX * NTY * NTZ;                // 2000 workgroups

// 512 threads = 8 waves; LDS 29.7KB -> 4 blocks/CU = 32 waves = 100% occ.
static const int BLK = 512;

// ws layout: [0, PCELLS*16)       float4 posid grid (x,y,z, id bits)
//            [PCELLS*16, +N*16)   float4 vel4 array (vx,vy,vz, 0)
// Wrap note: reference wraps mod 100 (torch.roll), but wrapped pairs are
// >= 4.9 apart while contact needs dist < 0.1 -> they contribute exactly 0.
// A negative-id halo (0xFF memset) reproduces that with no index arithmetic.

// Kernel 1: scatter particle pos+id into padded grid, pack vel as float4.
__global__ __launch_bounds__(256) void scatter_kernel(
    const float* __restrict__ x, const float* __restrict__ y, const float* __restrict__ z,
    const float* __restrict__ vx, const float* __restrict__ vy, const float* __restrict__ vz,
    const float* __restrict__ dptr,
    float4* __restrict__ posid, float4* __restrict__ vel4, int n)
{
    int i = blockIdx.x * blockDim.x + threadIdx.x;
    if (i >= n) return;
    float inv_d = 1.0f / dptr[0];
    float xi = x[i], yi = y[i], zi = z[i];
    // |jitter| <= 0.3*d, so roundf == jnp.round here (never near .5 boundary)
    int cx = (int)roundf(xi * inv_d);
    int cy = (int)roundf(yi * inv_d);
    int cz = (int)roundf(zi * inv_d);
    int cell = ((cz + 2) * PGD + (cy + 2)) * PGD + (cx + 2);
    float4 pv;
    pv.x = xi; pv.y = yi; pv.z = zi; pv.w = __int_as_float(i);
    posid[cell] = pv;
    float4 vv;
    vv.x = vx[i]; vv.y = vy[i]; vv.z = vz[i]; vv.w = 0.0f;
    vel4[i] = vv;
}

// Kernel 2: one workgroup per spatial tile. Stage halo pos+id into LDS,
// compact occupied cells, then 4 particles per wave (16 lanes x 8 passes).
// Probe loop is branchless (select-masked); the expensive damping body is
// deferred to a per-lane contact-bitmask while-loop (~2 iter/wave vs 8).
__global__ __launch_bounds__(BLK, 8) void force_kernel(
    const float* __restrict__ dptr, const float* __restrict__ knptr,
    const float* __restrict__ etaptr,
    const float4* __restrict__ posid, const float4* __restrict__ vel4,
    float* __restrict__ out, int n)
{
    __shared__ float4 tile[HCELLS];          // 28,224 B
    __shared__ unsigned short list[TCELLS];  // 1,000 B
    __shared__ int cnt;

    int b = blockIdx.x;
    int txi = b % NTX;
    int tyi = (b / NTX) % NTY;
    int tzi = b / (NTX * NTY);
    // Halo base in padded coords == tile origin in unpadded coords.
    int ox = txi * TX, oy = tyi * TY, oz = tzi * TZ;

    int t = threadIdx.x;
    if (t == 0) cnt = 0;

    // Phase 1: cooperative halo load (1764 float4s, x-rows contiguous).
    for (int l = t; l < HCELLS; l += BLK) {
        int lz = l / HPLANE;
        int r  = l - lz * HPLANE;
        int ly = r / HX;
        int lx = r - ly * HX;
        tile[l] = posid[((oz + lz) * PGD + (oy + ly)) * PGD + (ox + lx)];
    }
    __syncthreads();   // also publishes cnt = 0

    // Phase 1b: compact occupied interior cells.
    if (t < TCELLS) {
        int iz = t / (TX * TY);
        int r  = t - iz * (TX * TY);
        int iy = r / TX;
        int ix = r - iy * TX;
        int l = (iz + 2) * HPLANE + (iy + 2) * HX + (ix + 2);
        if (__float_as_int(tile[l].w) >= 0) {
            int pos = atomicAdd(&cnt, 1);
            list[pos] = (unsigned short)l;
        }
    }
    __syncthreads();
    int nOcc = cnt;
    if (nOcc == 0) return;

    float d   = dptr[0];
    float kn  = knptr[0];
    float eta = etaptr[0];
    float two_d = 2.0f * d;

    int lane = t & 63;
    int wv   = t >> 6;        // wave in block: 0..7
    int sub  = lane >> 4;     // 16-lane sub-group (particle slot): 0..3
    int l16  = lane & 15;

    // Per-lane stencil offsets: slot k = l16 + 16*j, j=0..7; k>124 -> center
    // (self, excluded by the valid test). Constant per lane.
    int offs[8];
    #pragma unroll
    for (int j = 0; j < 8; ++j) {
        int k = l16 + 16 * j;
        if (k > 124) k = 62;
        int sz = k / 25; int rr = k - sz * 25; int sy = rr / 5; int sx = rr - sy * 5;
        offs[j] = (sz - 2) * HPLANE + (sy - 2) * HX + (sx - 2);
    }

    // 32 particles per round (8 waves x 4 sub-groups).
    int nRounds = (nOcc + 31) >> 5;
    for (int rd = 0; rd < nRounds; ++rd) {
        int iw = rd * 32 + wv * 4 + sub;
        bool active = (iw < nOcc);
        int il = active ? iw : (nOcc - 1);   // clamped dup, store suppressed
        int c = list[il];                    // broadcast LDS read per sub-group
        float4 self = tile[c];
        int pid = __float_as_int(self.w);
        float4 pvel = vel4[pid];             // issued early, used in damping

        float fxc = 0.f, fyc = 0.f, fzc = 0.f;
        float fxd = 0.f, fyd = 0.f, fzd = 0.f;
        unsigned int cmask = 0;              // per-lane contact slots

        // Probe + spring loop: branchless. Empty/self slots get operands
        // selected so their contribution is exactly 0.0 (x + 0*0 == x).
        #pragma unroll
        for (int j = 0; j < 8; ++j) {
            float4 nb = tile[c + offs[j]];
            int B = __float_as_int(nb.w);
            bool valid = (B >= 0) & (B != pid);
            float nx = valid ? nb.x : self.x;   // -> dxp = 0 for invalid
            float ny = valid ? nb.y : self.y;
            float nz = valid ? nb.z : self.z;
            float dxp = self.x - nx;
            float dyp = self.y - ny;
            float dzp = self.z - nz;
            float d2 = dxp * dxp + dyp * dyp + dzp * dzp;
            float dist = __builtin_amdgcn_sqrtf(d2);   // v_sqrt_f32
            bool contact = valid & (dist < two_d);
            float denom   = fmaxf(1e-4f, dist);
            float inv_den = __builtin_amdgcn_rcpf(denom);  // v_rcp_f32
            float coef = contact ? kn * (dist - two_d) * inv_den : 0.0f;
            fxc += coef * dxp; fyc += coef * dyp; fzc += coef * dzp;
            cmask |= (contact ? 1u : 0u) << j;
        }

        // Deferred damping: per-lane iteration over actual contacts only
        // (avg ~0.2/lane; wave executes ~max popcount ~2 iterations).
        while (__builtin_amdgcn_ballot_w64(cmask != 0)) {
            if (cmask) {
                int j = __builtin_ctz(cmask);
                cmask &= cmask - 1;
                float4 nb = tile[c + offs[j]];     // LDS re-read, cheap
                int B = __float_as_int(nb.w);
                float dxp = self.x - nb.x;
                float dyp = self.y - nb.y;
                float dzp = self.z - nb.z;
                float d2 = dxp * dxp + dyp * dyp + dzp * dzp;
                float dist = __builtin_amdgcn_sqrtf(d2);
                float denom   = fmaxf(1e-4f, dist);
                float inv_den = __builtin_amdgcn_rcpf(denom);
                float4 bv = vel4[B];
                float dvxp = pvel.x - bv.x;
                float dvyp = pvel.y - bv.y;
                float dvzp = pvel.z - bv.z;
                float vn    = (dvxp * dxp + dvyp * dyp + dvzp * dzp) * inv_den;
                float dcoef = eta * vn * inv_den;
                fxd += dcoef * dxp; fyd += dcoef * dyp; fzd += dcoef * dzp;
            }
        }

        // 4-level butterfly within each 16-lane sub-group.
        #pragma unroll
        for (int off = 8; off >= 1; off >>= 1) {
            fxc += __shfl_xor(fxc, off, 16);
            fyc += __shfl_xor(fyc, off, 16);
            fzc += __shfl_xor(fzc, off, 16);
            fxd += __shfl_xor(fxd, off, 16);
            fyd += __shfl_xor(fyd, off, 16);
            fzd += __shfl_xor(fzd, off, 16);
        }

        if (active && l16 < 6) {
            float v = (l16 == 0) ? fxc
                    : (l16 == 1) ? fyc
                    : (l16 == 2) ? fzc
                    : (l16 == 3) ? fxd
                    : (l16 == 4) ? fyd : fzd;
            out[l16 * n + pid] = v;
        }
    }
}

extern "C" void kernel_launch(void* const* d_in, const int* in_sizes, int n_in,
                              void* d_out, int out_size, void* d_ws, size_t ws_size,
                              hipStream_t stream)
{
    const float* x     = (const float*)d_in[0];
    const float* y     = (const float*)d_in[1];
    const float* z     = (const float*)d_in[2];
    const float* vx    = (const float*)d_in[3];
    const float* vy    = (const float*)d_in[4];
    const float* vz    = (const float*)d_in[5];
    const float* dptr  = (const float*)d_in[6];
    const float* knptr = (const float*)d_in[7];
    const float* etap  = (const float*)d_in[8];
    // d_in[9] friction, d_in[10] dt: unused by the reference output.
    int n = in_sizes[0];

    float4* posid = (float4*)d_ws;                       // 18 MB padded grid
    float4* vel4  = (float4*)((char*)d_ws + (size_t)PCELLS * sizeof(float4));

    // 0xFF bytes -> id bits = -1 (empty); pos = NaN (rejected by id check).
    hipMemsetAsync(posid, 0xFF, (size_t)PCELLS * sizeof(float4), stream);

    int sblocks = (n + 255) / 256;
    scatter_kernel<<<sblocks, 256, 0, stream>>>(x, y, z, vx, vy, vz, dptr,
                                                posid, vel4, n);

    force_kernel<<<NTILES, BLK, 0, stream>>>(dptr, knptr, etap,
                                             posid, vel4, (float*)d_out, n);
}

// Round 16
// 119.915 us; speedup vs baseline: 1.1525x; 1.1525x over previous
//
#include <hip/hip_runtime.h>

// Problem constants (fixed by the reference's setup_inputs):
//   N = 100000 particles, D = 100 grid cells/dim, filter_size = 5 (radius 2).
// One particle per cell guaranteed (rng.choice replace=False).
static const int DG = 100;
static const int PGD = DG + 4;              // halo-padded dim: 104
static const int PCELLS = PGD * PGD * PGD;  // 1124864 cells

// Spatial tile per workgroup: 10 x 10 x 5 interior cells, +2 halo each side.
static const int TX = 10, TY = 10, TZ = 5;
static const int HX = TX + 4, HY = TY + 4, HZ = TZ + 4;   // 14,14,9
static const int HPLANE = HX * HY;                        // 196
static const int HCELLS = HPLANE * HZ;                    // 1764
static const int TCELLS = TX * TY * TZ;                   // 500
static const int NTX = DG / TX, NTY = DG / TY, NTZ = DG / TZ; // 10,10,20
static const int NTILES = NTX * NTY * NTZ;                // 2000 workgroups

// 512 threads = 8 waves; LDS 29.7KB allows 4 blocks/CU. NO min-waves clause:
// round 14 showed __launch_bounds__(512,8) caps VGPR at 32 -> scratch spills
// (WRITE_SIZE 19->104 MB, FETCH 44->95 MB, force +20us). Let RA pick VGPRs.
static const int BLK = 512;

// ws layout: [0, PCELLS*16)       float4 posid grid (x,y,z, id bits)
//            [PCELLS*16, +N*16)   float4 vel4 array (vx,vy,vz, 0)
// Wrap note: reference wraps mod 100 (torch.roll), but wrapped pairs are
// >= 4.9 apart while contact needs dist < 0.1 -> they contribute exactly 0.
// A negative-id halo (0xFF memset) reproduces that with no index arithmetic.

// Kernel 1: scatter particle pos+id into padded grid, pack vel as float4.
__global__ __launch_bounds__(256) void scatter_kernel(
    const float* __restrict__ x, const float* __restrict__ y, const float* __restrict__ z,
    const float* __restrict__ vx, const float* __restrict__ vy, const float* __restrict__ vz,
    const float* __restrict__ dptr,
    float4* __restrict__ posid, float4* __restrict__ vel4, int n)
{
    int i = blockIdx.x * blockDim.x + threadIdx.x;
    if (i >= n) return;
    float inv_d = 1.0f / dptr[0];
    float xi = x[i], yi = y[i], zi = z[i];
    // |jitter| <= 0.3*d, so roundf == jnp.round here (never near .5 boundary)
    int cx = (int)roundf(xi * inv_d);
    int cy = (int)roundf(yi * inv_d);
    int cz = (int)roundf(zi * inv_d);
    int cell = ((cz + 2) * PGD + (cy + 2)) * PGD + (cx + 2);
    float4 pv;
    pv.x = xi; pv.y = yi; pv.z = zi; pv.w = __int_as_float(i);
    posid[cell] = pv;
    float4 vv;
    vv.x = vx[i]; vv.y = vy[i]; vv.z = vz[i]; vv.w = 0.0f;
    vel4[i] = vv;
}

// Kernel 2: one workgroup per spatial tile. Stage halo pos+id into LDS,
// compact occupied cells, then 4 particles per wave (16 lanes x 8 passes).
// Probe loop is branchless (select-masked); the expensive damping body is
// deferred to a per-lane contact-bitmask while-loop (~2 iter/wave vs 8).
__global__ __launch_bounds__(BLK) void force_kernel(
    const float* __restrict__ dptr, const float* __restrict__ knptr,
    const float* __restrict__ etaptr,
    const float4* __restrict__ posid, const float4* __restrict__ vel4,
    float* __restrict__ out, int n)
{
    __shared__ float4 tile[HCELLS];          // 28,224 B
    __shared__ unsigned short list[TCELLS];  // 1,000 B
    __shared__ int cnt;

    int b = blockIdx.x;
    int txi = b % NTX;
    int tyi = (b / NTX) % NTY;
    int tzi = b / (NTX * NTY);
    // Halo base in padded coords == tile origin in unpadded coords.
    int ox = txi * TX, oy = tyi * TY, oz = tzi * TZ;

    int t = threadIdx.x;
    if (t == 0) cnt = 0;

    // Phase 1: cooperative halo load (1764 float4s, x-rows contiguous).
    for (int l = t; l < HCELLS; l += BLK) {
        int lz = l / HPLANE;
        int r  = l - lz * HPLANE;
        int ly = r / HX;
        int lx = r - ly * HX;
        tile[l] = posid[((oz + lz) * PGD + (oy + ly)) * PGD + (ox + lx)];
    }
    __syncthreads();   // also publishes cnt = 0

    // Phase 1b: compact occupied interior cells.
    if (t < TCELLS) {
        int iz = t / (TX * TY);
        int r  = t - iz * (TX * TY);
        int iy = r / TX;
        int ix = r - iy * TX;
        int l = (iz + 2) * HPLANE + (iy + 2) * HX + (ix + 2);
        if (__float_as_int(tile[l].w) >= 0) {
            int pos = atomicAdd(&cnt, 1);
            list[pos] = (unsigned short)l;
        }
    }
    __syncthreads();
    int nOcc = cnt;
    if (nOcc == 0) return;

    float d   = dptr[0];
    float kn  = knptr[0];
    float eta = etaptr[0];
    float two_d = 2.0f * d;

    int lane = t & 63;
    int wv   = t >> 6;        // wave in block: 0..7
    int sub  = lane >> 4;     // 16-lane sub-group (particle slot): 0..3
    int l16  = lane & 15;

    // Per-lane stencil offsets: slot k = l16 + 16*j, j=0..7; k>124 -> center
    // (self, excluded by the valid test). Constant per lane.
    int offs[8];
    #pragma unroll
    for (int j = 0; j < 8; ++j) {
        int k = l16 + 16 * j;
        if (k > 124) k = 62;
        int sz = k / 25; int rr = k - sz * 25; int sy = rr / 5; int sx = rr - sy * 5;
        offs[j] = (sz - 2) * HPLANE + (sy - 2) * HX + (sx - 2);
    }

    // 32 particles per round (8 waves x 4 sub-groups).
    int nRounds = (nOcc + 31) >> 5;
    for (int rd = 0; rd < nRounds; ++rd) {
        int iw = rd * 32 + wv * 4 + sub;
        bool active = (iw < nOcc);
        int il = active ? iw : (nOcc - 1);   // clamped dup, store suppressed
        int c = list[il];                    // broadcast LDS read per sub-group
        float4 self = tile[c];
        int pid = __float_as_int(self.w);
        float4 pvel = vel4[pid];             // issued early, used in damping

        float fxc = 0.f, fyc = 0.f, fzc = 0.f;
        float fxd = 0.f, fyd = 0.f, fzd = 0.f;
        unsigned int cmask = 0;              // per-lane contact slots

        // Probe + spring loop: branchless. Empty/self slots get operands
        // selected so their contribution is exactly 0.0 (x + 0*0 == x).
        #pragma unroll
        for (int j = 0; j < 8; ++j) {
            float4 nb = tile[c + offs[j]];
            int B = __float_as_int(nb.w);
            bool valid = (B >= 0) & (B != pid);
            float nx = valid ? nb.x : self.x;   // -> dxp = 0 for invalid
            float ny = valid ? nb.y : self.y;
            float nz = valid ? nb.z : self.z;
            float dxp = self.x - nx;
            float dyp = self.y - ny;
            float dzp = self.z - nz;
            float d2 = dxp * dxp + dyp * dyp + dzp * dzp;
            float dist = __builtin_amdgcn_sqrtf(d2);   // v_sqrt_f32
            bool contact = valid & (dist < two_d);
            float denom   = fmaxf(1e-4f, dist);
            float inv_den = __builtin_amdgcn_rcpf(denom);  // v_rcp_f32
            float coef = contact ? kn * (dist - two_d) * inv_den : 0.0f;
            fxc += coef * dxp; fyc += coef * dyp; fzc += coef * dzp;
            cmask |= (contact ? 1u : 0u) << j;
        }

        // Deferred damping: per-lane iteration over actual contacts only
        // (avg ~0.2/lane; wave executes ~max popcount ~2 iterations).
        while (__builtin_amdgcn_ballot_w64(cmask != 0)) {
            if (cmask) {
                int j = __builtin_ctz(cmask);
                cmask &= cmask - 1;
                float4 nb = tile[c + offs[j]];     // LDS re-read, cheap
                int B = __float_as_int(nb.w);
                float dxp = self.x - nb.x;
                float dyp = self.y - nb.y;
                float dzp = self.z - nb.z;
                float d2 = dxp * dxp + dyp * dyp + dzp * dzp;
                float dist = __builtin_amdgcn_sqrtf(d2);
                float denom   = fmaxf(1e-4f, dist);
                float inv_den = __builtin_amdgcn_rcpf(denom);
                float4 bv = vel4[B];
                float dvxp = pvel.x - bv.x;
                float dvyp = pvel.y - bv.y;
                float dvzp = pvel.z - bv.z;
                float vn    = (dvxp * dxp + dvyp * dyp + dvzp * dzp) * inv_den;
                float dcoef = eta * vn * inv_den;
                fxd += dcoef * dxp; fyd += dcoef * dyp; fzd += dcoef * dzp;
            }
        }

        // 4-level butterfly within each 16-lane sub-group.
        #pragma unroll
        for (int off = 8; off >= 1; off >>= 1) {
            fxc += __shfl_xor(fxc, off, 16);
            fyc += __shfl_xor(fyc, off, 16);
            fzc += __shfl_xor(fzc, off, 16);
            fxd += __shfl_xor(fxd, off, 16);
            fyd += __shfl_xor(fyd, off, 16);
            fzd += __shfl_xor(fzd, off, 16);
        }

        if (active && l16 < 6) {
            float v = (l16 == 0) ? fxc
                    : (l16 == 1) ? fyc
                    : (l16 == 2) ? fzc
                    : (l16 == 3) ? fxd
                    : (l16 == 4) ? fyd : fzd;
            out[l16 * n + pid] = v;
        }
    }
}

extern "C" void kernel_launch(void* const* d_in, const int* in_sizes, int n_in,
                              void* d_out, int out_size, void* d_ws, size_t ws_size,
                              hipStream_t stream)
{
    const float* x     = (const float*)d_in[0];
    const float* y     = (const float*)d_in[1];
    const float* z     = (const float*)d_in[2];
    const float* vx    = (const float*)d_in[3];
    const float* vy    = (const float*)d_in[4];
    const float* vz    = (const float*)d_in[5];
    const float* dptr  = (const float*)d_in[6];
    const float* knptr = (const float*)d_in[7];
    const float* etap  = (const float*)d_in[8];
    // d_in[9] friction, d_in[10] dt: unused by the reference output.
    int n = in_sizes[0];

    float4* posid = (float4*)d_ws;                       // 18 MB padded grid
    float4* vel4  = (float4*)((char*)d_ws + (size_t)PCELLS * sizeof(float4));

    // 0xFF bytes -> id bits = -1 (empty); pos = NaN (rejected by id check).
    hipMemsetAsync(posid, 0xFF, (size_t)PCELLS * sizeof(float4), stream);

    int sblocks = (n + 255) / 256;
    scatter_kernel<<<sblocks, 256, 0, stream>>>(x, y, z, vx, vy, vz, dptr,
                                                posid, vel4, n);

    force_kernel<<<NTILES, BLK, 0, stream>>>(dptr, knptr, etap,
                                             posid, vel4, (float*)d_out, n);
}